// Round 5
// baseline (158.829 us; speedup 1.0000x reference)
//
#include <hip/hip_runtime.h>
#include <hip/hip_bf16.h>

#define NP 300
#define PM 320
#define HID 4069
#define KD 25088
#define FW 37
#define FC 512

#define BK 64

// ---- gemm1 geometry: BM=320, BN1=128, BK=64, KSPLIT1=8, A triple-buffered ----
#define BN1 128
#define KSPLIT1 8
#define KC1 (KD/KSPLIT1)        // 3136
#define NSTEP1 (KC1/BK)         // 49
#define A1BYTES (PM*BK*2)       // 40960
#define B1BYTES (BN1*BK*2)      // 16384
// LDS: 3*A1BYTES + 2*B1BYTES = 122880 + 32768 = 155648 B (152 KiB)

// ---- gemm2 geometry: BN=64, split-K over 4096-padded K ----
#define BN 64
#define ABYTES (PM*BK*2)        // 40960
#define BUFBYTES (ABYTES + BN*BK*2)  // 49152
#define K2PAD 4096
#define KSL 32
#define KC2 (K2PAD/KSL)         // 128
#define NSTEP2 (KC2/BK)         // 2

typedef __attribute__((ext_vector_type(4))) float f32x4;
typedef __attribute__((ext_vector_type(8))) short bf16x8;

__device__ inline unsigned short f2bf(float x) {
  __hip_bfloat16 h = __float2bfloat16(x);
  return *reinterpret_cast<unsigned short*>(&h);
}

// ---------------- ROI pool: (37,37,512) + (300,4) -> bf16 [320][25088] ----------------
__global__ void roi_pool_k(const float* __restrict__ fmap,
                           const float* __restrict__ props,
                           unsigned short* __restrict__ pooled) {
  int p = blockIdx.x;
  int t = threadIdx.x;
  if (p >= NP) {
    unsigned int* row = (unsigned int*)(pooled + (size_t)p * KD);
    for (int i = t; i < KD/2; i += 256) row[i] = 0u;
    return;
  }
  float y1 = props[p*4+0], x1 = props[p*4+1], y2 = props[p*4+2], x2 = props[p*4+3];
  int c = t * 2;
  for (int py = 0; py < 7; ++py) {
    float ty = (float)py * (1.0f/6.0f);
    float ys = (y1 + ty * (y2 - y1)) * 36.0f;
    ys = fminf(fmaxf(ys, 0.0f), 36.0f);
    int y0 = (int)floorf(ys);
    y0 = min(max(y0, 0), 35);
    float yf = ys - (float)y0;
    for (int px = 0; px < 7; ++px) {
      float tx = (float)px * (1.0f/6.0f);
      float xs = (x1 + tx * (x2 - x1)) * 36.0f;
      xs = fminf(fmaxf(xs, 0.0f), 36.0f);
      int x0 = (int)floorf(xs);
      x0 = min(max(x0, 0), 35);
      float xf = xs - (float)x0;
      const float* base = fmap + ((size_t)y0 * FW + x0) * FC + c;
      float2 tl = *(const float2*)(base);
      float2 tr = *(const float2*)(base + FC);
      float2 bl = *(const float2*)(base + FW*FC);
      float2 br = *(const float2*)(base + FW*FC + FC);
      float tpx = tl.x*(1.f-xf) + tr.x*xf;
      float tpy = tl.y*(1.f-xf) + tr.y*xf;
      float btx = bl.x*(1.f-xf) + br.x*xf;
      float bty = bl.y*(1.f-xf) + br.y*xf;
      float vx = tpx*(1.f-yf) + btx*yf;
      float vy = tpy*(1.f-yf) + bty*yf;
      unsigned int packed = (unsigned int)f2bf(vx) | ((unsigned int)f2bf(vy) << 16);
      *(unsigned int*)(pooled + (size_t)p*KD + ((py*7+px)*FC + c)) = packed;
    }
  }
}

// ---------------- GEMM1: A[320][25088]bf16 x W1[25088][4069]f32 -> partials f32 ----------------
// A triple-buffered (stage s+2), B double-buffered (load s+2, write s+1).
// Barrier vmcnt(21) retires only PREV-step A-staging; no same-step VMEM on the barrier path.
__global__ __launch_bounds__(512, 2)
void gemm1_k(const unsigned short* __restrict__ A,
             const float* __restrict__ W1,
             float* __restrict__ part) {
  __shared__ char ldsA[3*A1BYTES];   // 120 KiB
  __shared__ char ldsB[2*B1BYTES];   // 32 KiB
  const int t = threadIdx.x;
  const int wave = t >> 6;
  const int lane = t & 63;
  const int bid = blockIdx.x;       // 0..255
  const int kc = bid & 7;           // same kc -> same XCD under round-robin (A-chunk L2-resident)
  const int ntile = bid >> 3;       // 0..31
  const int n0 = ntile * BN1;
  const int kstart0 = kc * KC1;

  // B load geometry: thread -> (col, 16 k's)
  const int bcol = t & 127;
  const int bkg  = t >> 7;          // 0..3 -> k base bkg*16
  const int ngc  = min(n0 + bcol, HID-1);
  const int c7m  = (bcol & 7) << 4;
  const int bw0 = bcol*128 + ((bkg*32)      ^ c7m);
  const int bw1 = bcol*128 + ((bkg*32 + 16) ^ c7m);

  const int wm = wave >> 1;   // 0..3 -> 80 rows
  const int wn = wave & 1;    // 0..1 -> 64 cols

  int aoff[5][2], boff[4][2];
  #pragma unroll
  for (int fm = 0; fm < 5; ++fm) {
    int row = wm*80 + fm*16 + (lane & 15);
    #pragma unroll
    for (int h = 0; h < 2; ++h) {
      int kb = (h << 6) | ((lane >> 4) << 4);
      aoff[fm][h] = row*128 + (kb ^ ((row & 7) << 4));
    }
  }
  #pragma unroll
  for (int fn = 0; fn < 4; ++fn) {
    int col = wn*64 + fn*16 + (lane & 15);
    #pragma unroll
    for (int h = 0; h < 2; ++h) {
      int kb = (h << 6) | ((lane >> 4) << 4);
      boff[fn][h] = col*128 + (kb ^ ((col & 7) << 4));
    }
  }

  f32x4 acc[5][4];
  #pragma unroll
  for (int fm=0; fm<5; ++fm)
    #pragma unroll
    for (int fn=0; fn<4; ++fn)
      acc[fm][fn] = (f32x4){0.f,0.f,0.f,0.f};

  auto stageA = [&](int s, int abuf) {  // 40 KB tile, linear dest + inverse-swizzled source
    const int kstart = kstart0 + s*BK;
    char* dstbase = ldsA + abuf*A1BYTES;
    #pragma unroll
    for (int i = 0; i < 5; ++i) {
      int chunk = wave*5 + i;
      int o = chunk*1024 + lane*16;
      int row = o >> 7;
      int kb = (o & 127) ^ ((row & 7) << 4);
      const char* g = (const char*)A + (size_t)row*(KD*2) + (size_t)kstart*2 + kb;
      __builtin_amdgcn_global_load_lds(
          (const __attribute__((address_space(1))) unsigned int*)g,
          (__attribute__((address_space(3))) unsigned int*)(dstbase + chunk*1024),
          16, 0, 0);
    }
  };
  auto compute = [&](int abuf, int bbuf) {
    const char* abase = ldsA + abuf*A1BYTES;
    const char* bbase = ldsB + bbuf*B1BYTES;
    #pragma unroll
    for (int h = 0; h < 2; ++h) {
      bf16x8 af[5], bfr[4];
      #pragma unroll
      for (int fm = 0; fm < 5; ++fm) af[fm] = *(const bf16x8*)(abase + aoff[fm][h]);
      #pragma unroll
      for (int fn = 0; fn < 4; ++fn) bfr[fn] = *(const bf16x8*)(bbase + boff[fn][h]);
      #pragma unroll
      for (int fm = 0; fm < 5; ++fm)
        #pragma unroll
        for (int fn = 0; fn < 4; ++fn)
          acc[fm][fn] = __builtin_amdgcn_mfma_f32_16x16x32_bf16(af[fm], bfr[fn], acc[fm][fn], 0, 0, 0);
    }
  };

#define LOADB(s, bv) do {                                                     \
    const float* _src = W1 + (size_t)((kstart0 + (s)*BK) + bkg*16) * HID + ngc; \
    _Pragma("unroll")                                                         \
    for (int _i = 0; _i < 16; ++_i) bv[_i] = _src[(size_t)_i * HID];          \
  } while (0)

#define WRITEB(bv, bbuf) do {                                                 \
    bf16x8 _b0, _b1;                                                          \
    _Pragma("unroll")                                                         \
    for (int _i = 0; _i < 8; ++_i) { _b0[_i] = (short)f2bf(bv[_i]);           \
                                     _b1[_i] = (short)f2bf(bv[8+_i]); }       \
    *(bf16x8*)(ldsB + (bbuf)*B1BYTES + bw0) = _b0;                            \
    *(bf16x8*)(ldsB + (bbuf)*B1BYTES + bw1) = _b1;                            \
  } while (0)

  float bvA[16], bvB[16];

  // ---- prologue ----
  // B(0) issued FIRST so WRITEB's compiler wait (vmcnt(10)) keeps A(0),A(1) in flight.
  LOADB(0, bvA);
  stageA(0, 0);
  stageA(1, 1);
  WRITEB(bvA, 0);
  LOADB(1, bvA);
  // outstanding: A(0)5 (oldest), A(1)5, B(1)16 -> retire A(0) only
  asm volatile("s_waitcnt vmcnt(21) lgkmcnt(0)" ::: "memory");
  __builtin_amdgcn_s_barrier();
  __builtin_amdgcn_sched_barrier(0);

  // STEP(s): stage A(s+2), load B(s+2), compute(s), write B(s+1).
  // At barrier, outstanding = A(s+1)5 [prev step, oldest] + A(s+2)5 + B(s+2)16 = 26.
  // vmcnt(21) retires A(s+1) only -- staged a full step ago (latency already hidden).
#define STEP(s, bvC, bvO, AC, AS) do {                                \
    stageA((s)+2, AS);                                                \
    LOADB((s)+2, bvO);                                                \
    compute(AC, (s)&1);                                               \
    WRITEB(bvC, ((s)&1)^1);                                           \
    asm volatile("s_waitcnt vmcnt(21) lgkmcnt(0)" ::: "memory");      \
    __builtin_amdgcn_s_barrier();                                     \
    __builtin_amdgcn_sched_barrier(0);                                \
  } while (0)

  int ac = 0;   // abuf index of A(s) at loop top (== s % 3)
  for (int s = 0; s + 3 < NSTEP1; s += 2) {   // s = 0,2,...,44 -> steps 0..45
    int as0 = (ac >= 1) ? ac - 1 : ac + 2;    // (ac+2)%3
    STEP(s, bvA, bvB, ac, as0);
    int ac1 = (ac + 1 >= 3) ? 0 : ac + 1;     // (ac+1)%3
    STEP(s + 1, bvB, bvA, ac1, ac);           // stage buf (s+3)%3 == ac
    ac = (ac1 + 1 >= 3) ? 0 : ac1 + 1;
  }
  // ac == 46%3 == 1 here.
  STEP(46, bvA, bvB, 1, 0);                   // stages A(48)->buf0, loads B(48)->bvB
  { // s = 47: no more issues
    compute(2, 1);
    WRITEB(bvB, 0);
    asm volatile("s_waitcnt vmcnt(0) lgkmcnt(0)" ::: "memory");
    __builtin_amdgcn_s_barrier();
    __builtin_amdgcn_sched_barrier(0);
  }
  compute(0, 0);                              // s = 48

#undef STEP
#undef LOADB
#undef WRITEB

  float* dst = part + (size_t)kc * NP * HID;
  #pragma unroll
  for (int fm = 0; fm < 5; ++fm) {
    #pragma unroll
    for (int fn = 0; fn < 4; ++fn) {
      int ncol = n0 + wn*64 + fn*16 + (lane & 15);
      #pragma unroll
      for (int j = 0; j < 4; ++j) {
        int m = wm*80 + fm*16 + ((lane >> 4) * 4) + j;
        if (m < NP && ncol < HID)
          dst[(size_t)m * HID + ncol] = acc[fm][fn][j];
      }
    }
  }
}

// ---------------- reduce 8 partials + bias + relu -> h bf16 [320][4096] ----------------
__global__ void reduce_k(const float* __restrict__ part,
                         const float* __restrict__ b1,
                         unsigned short* __restrict__ hb) {
  int n = blockIdx.x * 256 + threadIdx.x;
  int p = blockIdx.y;
  if (n >= K2PAD) return;
  float v = 0.0f;
  if (n < HID) {
    size_t i = (size_t)p * HID + n;
    const size_t S = (size_t)NP * HID;
    float s0 = 0.f;
    #pragma unroll
    for (int k = 0; k < KSPLIT1; ++k) s0 += part[i + (size_t)k*S];
    v = fmaxf(s0 + b1[n], 0.0f);
  }
  hb[(size_t)p * K2PAD + n] = f2bf(v);
}

// ---------------- GEMM2 (MFMA split-K): hb[320][4096] x [Wc|Wr|0][4096][128] -> part2 ----------------
__global__ __launch_bounds__(512, 1)
void gemm2_k(const unsigned short* __restrict__ hb,
             const float* __restrict__ Wc,
             const float* __restrict__ Wr,
             float* __restrict__ part2) {
  __shared__ char lds[2*BUFBYTES];
  const int t = threadIdx.x;
  const int wave = t >> 6;
  const int lane = t & 63;
  const int ntile = blockIdx.x;
  const int kc = blockIdx.y;
  const int n0 = ntile * BN;
  const int kstart0 = kc * KC2;

  const int bn_l = t & 63;
  const int bk8  = (t >> 6) * 8;
  const int jn   = n0 + bn_l;
  const float* bsrc; int bst;
  if (jn < 21)        { bsrc = Wc + jn;        bst = 21; }
  else if (jn < 101)  { bsrc = Wr + (jn - 21); bst = 80; }
  else                { bsrc = nullptr;        bst = 0;  }
  const int bwoff = ABYTES + bn_l*128 + ((bk8*2) ^ ((bn_l & 7) << 4));

  const int wm = wave >> 1;
  const int wn = wave & 1;

  int aoff[5][2], boff[2][2];
  #pragma unroll
  for (int fm = 0; fm < 5; ++fm) {
    int row = wm*80 + fm*16 + (lane & 15);
    #pragma unroll
    for (int h = 0; h < 2; ++h) {
      int kb = (h << 6) | ((lane >> 4) << 4);
      aoff[fm][h] = row*128 + (kb ^ ((row & 7) << 4));
    }
  }
  #pragma unroll
  for (int fn = 0; fn < 2; ++fn) {
    int col = wn*32 + fn*16 + (lane & 15);
    #pragma unroll
    for (int h = 0; h < 2; ++h) {
      int kb = (h << 6) | ((lane >> 4) << 4);
      boff[fn][h] = ABYTES + col*128 + (kb ^ ((col & 7) << 4));
    }
  }

  f32x4 acc[5][2];
  #pragma unroll
  for (int fm=0; fm<5; ++fm)
    #pragma unroll
    for (int fn=0; fn<2; ++fn)
      acc[fm][fn] = (f32x4){0.f,0.f,0.f,0.f};

  auto stageA = [&](int s, int buf) {
    const int kstart = kstart0 + s*BK;
    char* dstbase = lds + buf*BUFBYTES;
    #pragma unroll
    for (int i = 0; i < 5; ++i) {
      int chunk = wave*5 + i;
      int o = chunk*1024 + lane*16;
      int row = o >> 7;
      int kb = (o & 127) ^ ((row & 7) << 4);
      const char* g = (const char*)hb + (size_t)row*(K2PAD*2) + (size_t)kstart*2 + kb;
      __builtin_amdgcn_global_load_lds(
          (const __attribute__((address_space(1))) unsigned int*)g,
          (__attribute__((address_space(3))) unsigned int*)(dstbase + chunk*1024),
          16, 0, 0);
    }
  };
  auto loadB = [&](int s, float* bv) {
    const int kstart = kstart0 + s*BK;
    #pragma unroll
    for (int i = 0; i < 8; ++i) {
      int k = kstart + bk8 + i;
      bv[i] = (bsrc && k < HID) ? bsrc[(size_t)k * bst] : 0.0f;
    }
  };
  auto writeB = [&](const float* bv, int buf) {
    bf16x8 bb;
    #pragma unroll
    for (int i = 0; i < 8; ++i) bb[i] = (short)f2bf(bv[i]);
    *(bf16x8*)(lds + buf*BUFBYTES + bwoff) = bb;
  };
  auto compute = [&](int buf) {
    const char* base = lds + buf*BUFBYTES;
    #pragma unroll
    for (int h = 0; h < 2; ++h) {
      bf16x8 af[5], bfr[2];
      #pragma unroll
      for (int fm = 0; fm < 5; ++fm) af[fm] = *(const bf16x8*)(base + aoff[fm][h]);
      #pragma unroll
      for (int fn = 0; fn < 2; ++fn) bfr[fn] = *(const bf16x8*)(base + boff[fn][h]);
      #pragma unroll
      for (int fm = 0; fm < 5; ++fm)
        #pragma unroll
        for (int fn = 0; fn < 2; ++fn)
          acc[fm][fn] = __builtin_amdgcn_mfma_f32_16x16x32_bf16(af[fm], bfr[fn], acc[fm][fn], 0, 0, 0);
    }
  };

  {
    float bv[8];
    loadB(0, bv);
    stageA(0, 0);
    writeB(bv, 0);
  }
  __syncthreads();

  for (int s = 0; s < NSTEP2; ++s) {
    int cur = s & 1;
    float bv[8];
    if (s + 1 < NSTEP2) {
      loadB(s+1, bv);
      stageA(s+1, cur^1);
    }
    compute(cur);
    if (s + 1 < NSTEP2) {
      writeB(bv, cur^1);
    }
    __syncthreads();
  }

  float* dst = part2 + (size_t)kc * PM * 128;
  #pragma unroll
  for (int fm = 0; fm < 5; ++fm) {
    #pragma unroll
    for (int fn = 0; fn < 2; ++fn) {
      int ncol = n0 + wn*32 + fn*16 + (lane & 15);
      #pragma unroll
      for (int j = 0; j < 4; ++j) {
        int m = wm*80 + fm*16 + ((lane >> 4) * 4) + j;
        dst[(size_t)m * 128 + ncol] = acc[fm][fn][j];
      }
    }
  }
}

// ---------------- reduce2: sum K-slices + bias -> out ----------------
__global__ void reduce2_k(const float* __restrict__ part2,
                          const float* __restrict__ bc,
                          const float* __restrict__ br,
                          float* __restrict__ out) {
  int p = blockIdx.x;
  int j = threadIdx.x;
  if (j >= 101) return;
  float s = 0.0f;
  #pragma unroll 8
  for (int k = 0; k < KSL; ++k)
    s += part2[(size_t)k * PM * 128 + (size_t)p * 128 + j];
  if (j < 21) out[(size_t)p*21 + j] = s + bc[j];
  else        out[6300 + (size_t)p*80 + (j-21)] = s + br[j-21];
}

extern "C" void kernel_launch(void* const* d_in, const int* in_sizes, int n_in,
                              void* d_out, int out_size, void* d_ws, size_t ws_size,
                              hipStream_t stream) {
  const float* fmap  = (const float*)d_in[0];
  const float* props = (const float*)d_in[1];
  const float* W1    = (const float*)d_in[2];
  const float* b1    = (const float*)d_in[3];
  const float* Wc    = (const float*)d_in[4];
  const float* bc    = (const float*)d_in[5];
  const float* Wr    = (const float*)d_in[6];
  const float* br    = (const float*)d_in[7];
  float* out = (float*)d_out;
  char* ws = (char*)d_ws;

  unsigned short* pooled = (unsigned short*)ws;                     // 16,056,320 B
  float* part = (float*)(ws + 16056320);                            // 8*300*4069*4 = 39,062,400 B
  unsigned short* hb = (unsigned short*)(ws + 16056320 + 39062400); //  2,621,440 B
  float* part2 = (float*)(ws + 16056320 + 39062400 + 2621440);      //  5,242,880 B

  roi_pool_k<<<PM, 256, 0, stream>>>(fmap, props, pooled);
  gemm1_k<<<256, 512, 0, stream>>>(pooled, W1, part);
  reduce_k<<<dim3(K2PAD/256, NP), 256, 0, stream>>>(part, b1, hb);
  gemm2_k<<<dim3(2, KSL), 512, 0, stream>>>(hb, Wc, Wr, part2);
  reduce2_k<<<NP, 128, 0, stream>>>(part2, bc, br, out);
}

// Round 6
// 145.414 us; speedup vs baseline: 1.0923x; 1.0923x over previous
//
#include <hip/hip_runtime.h>
#include <hip/hip_bf16.h>

#define NP 300
#define PM 320
#define HID 4069
#define KD 25088
#define FW 37
#define FC 512

#define BK 64

// ---- gemm1 geometry: BM=320, BN1=128, BK=64, KSPLIT1=8 ----
#define BN1 128
#define KSPLIT1 8
#define KC1 (KD/KSPLIT1)        // 3136
#define NSTEP1 (KC1/BK)         // 49
#define A1BYTES (PM*BK*2)       // 40960
#define B1BYTES (BN1*BK*2)      // 16384
#define BUF1 (A1BYTES + B1BYTES) // 57344 (2 bufs = 112 KiB LDS)

// ---- gemm2 geometry: BN=64, split-K over 4096-padded K ----
#define BN 64
#define ABYTES (PM*BK*2)        // 40960
#define BUFBYTES (ABYTES + BN*BK*2)  // 49152
#define K2PAD 4096
#define KSL 32
#define KC2 (K2PAD/KSL)         // 128
#define NSTEP2 (KC2/BK)         // 2

typedef __attribute__((ext_vector_type(4))) float f32x4;
typedef __attribute__((ext_vector_type(8))) short bf16x8;

__device__ inline unsigned short f2bf(float x) {
  __hip_bfloat16 h = __float2bfloat16(x);
  return *reinterpret_cast<unsigned short*>(&h);
}

// ---------------- ROI pool: (37,37,512) + (300,4) -> bf16 [320][25088] ----------------
__global__ void roi_pool_k(const float* __restrict__ fmap,
                           const float* __restrict__ props,
                           unsigned short* __restrict__ pooled) {
  int p = blockIdx.x;
  int t = threadIdx.x;
  if (p >= NP) {
    unsigned int* row = (unsigned int*)(pooled + (size_t)p * KD);
    for (int i = t; i < KD/2; i += 256) row[i] = 0u;
    return;
  }
  float y1 = props[p*4+0], x1 = props[p*4+1], y2 = props[p*4+2], x2 = props[p*4+3];
  int c = t * 2;
  for (int py = 0; py < 7; ++py) {
    float ty = (float)py * (1.0f/6.0f);
    float ys = (y1 + ty * (y2 - y1)) * 36.0f;
    ys = fminf(fmaxf(ys, 0.0f), 36.0f);
    int y0 = (int)floorf(ys);
    y0 = min(max(y0, 0), 35);
    float yf = ys - (float)y0;
    for (int px = 0; px < 7; ++px) {
      float tx = (float)px * (1.0f/6.0f);
      float xs = (x1 + tx * (x2 - x1)) * 36.0f;
      xs = fminf(fmaxf(xs, 0.0f), 36.0f);
      int x0 = (int)floorf(xs);
      x0 = min(max(x0, 0), 35);
      float xf = xs - (float)x0;
      const float* base = fmap + ((size_t)y0 * FW + x0) * FC + c;
      float2 tl = *(const float2*)(base);
      float2 tr = *(const float2*)(base + FC);
      float2 bl = *(const float2*)(base + FW*FC);
      float2 br = *(const float2*)(base + FW*FC + FC);
      float tpx = tl.x*(1.f-xf) + tr.x*xf;
      float tpy = tl.y*(1.f-xf) + tr.y*xf;
      float btx = bl.x*(1.f-xf) + br.x*xf;
      float bty = bl.y*(1.f-xf) + br.y*xf;
      float vx = tpx*(1.f-yf) + btx*yf;
      float vy = tpy*(1.f-yf) + bty*yf;
      unsigned int packed = (unsigned int)f2bf(vx) | ((unsigned int)f2bf(vy) << 16);
      *(unsigned int*)(pooled + (size_t)p*KD + ((py*7+px)*FC + c)) = packed;
    }
  }
}

// ---------------- GEMM1: A[320][25088]bf16 x W1[25088][4069]f32 -> partials f32 ----------------
// R4 skeleton (A dbuf, counted vmcnt(16)) + m201-style 2-phase interleave + setprio.
__global__ __launch_bounds__(512, 2)
void gemm1_k(const unsigned short* __restrict__ A,
             const float* __restrict__ W1,
             float* __restrict__ part) {
  __shared__ char lds[2*BUF1];   // 112 KiB
  const int t = threadIdx.x;
  const int wave = t >> 6;
  const int lane = t & 63;
  const int bid = blockIdx.x;       // 0..255
  const int kc = bid & 7;           // same kc -> same XCD under round-robin
  const int ntile = bid >> 3;       // 0..31
  const int n0 = ntile * BN1;
  const int kstart0 = kc * KC1;

  // B load geometry: thread -> (col, 16 k's)
  const int bcol = t & 127;
  const int bkg  = t >> 7;          // 0..3 -> k base bkg*16
  const int ngc  = min(n0 + bcol, HID-1);
  const int c7m  = (bcol & 7) << 4;
  const int bw0 = A1BYTES + bcol*128 + ((bkg*32)      ^ c7m);
  const int bw1 = A1BYTES + bcol*128 + ((bkg*32 + 16) ^ c7m);

  const int wm = wave >> 1;   // 0..3 -> 80 rows
  const int wn = wave & 1;    // 0..1 -> 64 cols

  int aoff[5][2], boff[4][2];
  #pragma unroll
  for (int fm = 0; fm < 5; ++fm) {
    int row = wm*80 + fm*16 + (lane & 15);
    #pragma unroll
    for (int h = 0; h < 2; ++h) {
      int kb = (h << 6) | ((lane >> 4) << 4);
      aoff[fm][h] = row*128 + (kb ^ ((row & 7) << 4));
    }
  }
  #pragma unroll
  for (int fn = 0; fn < 4; ++fn) {
    int col = wn*64 + fn*16 + (lane & 15);
    #pragma unroll
    for (int h = 0; h < 2; ++h) {
      int kb = (h << 6) | ((lane >> 4) << 4);
      boff[fn][h] = A1BYTES + col*128 + (kb ^ ((col & 7) << 4));
    }
  }

  f32x4 acc[5][4];
  #pragma unroll
  for (int fm=0; fm<5; ++fm)
    #pragma unroll
    for (int fn=0; fn<4; ++fn)
      acc[fm][fn] = (f32x4){0.f,0.f,0.f,0.f};

  auto stageA = [&](int s, int buf) {  // 40 KB tile, linear dest + inverse-swizzled source
    const int kstart = kstart0 + s*BK;
    char* dstbase = lds + buf*BUF1;
    #pragma unroll
    for (int i = 0; i < 5; ++i) {
      int chunk = wave*5 + i;
      int o = chunk*1024 + lane*16;
      int row = o >> 7;
      int kb = (o & 127) ^ ((row & 7) << 4);
      const char* g = (const char*)A + (size_t)row*(KD*2) + (size_t)kstart*2 + kb;
      __builtin_amdgcn_global_load_lds(
          (const __attribute__((address_space(1))) unsigned int*)g,
          (__attribute__((address_space(3))) unsigned int*)(dstbase + chunk*1024),
          16, 0, 0);
    }
  };

#define LOADB(s, bv) do {                                                     \
    const float* _src = W1 + (size_t)((kstart0 + (s)*BK) + bkg*16) * HID + ngc; \
    _Pragma("unroll")                                                         \
    for (int _i = 0; _i < 16; ++_i) bv[_i] = _src[(size_t)_i * HID];          \
  } while (0)

#define WRITEB(bv, buf) do {                                                  \
    bf16x8 _b0, _b1;                                                          \
    _Pragma("unroll")                                                         \
    for (int _i = 0; _i < 8; ++_i) { _b0[_i] = (short)f2bf(bv[_i]);           \
                                     _b1[_i] = (short)f2bf(bv[8+_i]); }       \
    *(bf16x8*)(lds + (buf)*BUF1 + bw0) = _b0;                                 \
    *(bf16x8*)(lds + (buf)*BUF1 + bw1) = _b1;                                 \
  } while (0)

#define RDFRAGS(buf, h, af, bfv) do {                                         \
    const char* _b = lds + (buf)*BUF1;                                        \
    _Pragma("unroll")                                                         \
    for (int _f = 0; _f < 5; ++_f) af[_f] = *(const bf16x8*)(_b + aoff[_f][h]); \
    _Pragma("unroll")                                                         \
    for (int _f = 0; _f < 4; ++_f) bfv[_f] = *(const bf16x8*)(_b + boff[_f][h]); \
  } while (0)

#define MFMAH(af, bfv) do {                                                   \
    _Pragma("unroll")                                                         \
    for (int _m = 0; _m < 5; ++_m)                                            \
      _Pragma("unroll")                                                       \
      for (int _n = 0; _n < 4; ++_n)                                          \
        acc[_m][_n] = __builtin_amdgcn_mfma_f32_16x16x32_bf16(af[_m], bfv[_n], acc[_m][_n], 0, 0, 0); \
  } while (0)

  float bvA[16], bvB[16];

  // ---- prologue: tile 0 -> buf0; preload B(1) ----
  stageA(0, 0);
  LOADB(0, bvA);
  WRITEB(bvA, 0);
  LOADB(1, bvA);
  asm volatile("s_waitcnt vmcnt(16) lgkmcnt(0)" ::: "memory");
  __builtin_amdgcn_s_barrier();
  __builtin_amdgcn_sched_barrier(0);

  // STEP(s): two m201-style phases.
  //  ph0: ds_read h0 frags + issue stageA(s+1) -> barrier -> lgkm(0) -> MFMA h0
  //  ph1: ds_read h1 frags + issue LOADB(s+2)  -> barrier -> lgkm(0) -> MFMA h1
  //  then WRITEB(B(s+1)) [compiler vmcnt(21) keeps A(s+1)+B(s+2) in flight],
  //  vmcnt(16) retires A(s+1), final barrier.
#define STEP(s, bvC, bvO) do {                                        \
    {                                                                 \
      bf16x8 af0[5], bf0[4];                                          \
      RDFRAGS((s)&1, 0, af0, bf0);                                    \
      stageA((s)+1, ((s)&1)^1);                                       \
      __builtin_amdgcn_s_barrier();                                   \
      asm volatile("s_waitcnt lgkmcnt(0)" ::: "memory");              \
      __builtin_amdgcn_sched_barrier(0);                              \
      __builtin_amdgcn_s_setprio(1);                                  \
      MFMAH(af0, bf0);                                                \
      __builtin_amdgcn_s_setprio(0);                                  \
    }                                                                 \
    {                                                                 \
      bf16x8 af1[5], bf1[4];                                          \
      RDFRAGS((s)&1, 1, af1, bf1);                                    \
      LOADB((s)+2, bvO);                                              \
      __builtin_amdgcn_s_barrier();                                   \
      asm volatile("s_waitcnt lgkmcnt(0)" ::: "memory");              \
      __builtin_amdgcn_sched_barrier(0);                              \
      __builtin_amdgcn_s_setprio(1);                                  \
      MFMAH(af1, bf1);                                                \
      __builtin_amdgcn_s_setprio(0);                                  \
    }                                                                 \
    WRITEB(bvC, ((s)&1)^1);                                           \
    asm volatile("s_waitcnt vmcnt(16) lgkmcnt(0)" ::: "memory");      \
    __builtin_amdgcn_s_barrier();                                     \
    __builtin_amdgcn_sched_barrier(0);                                \
  } while (0)

  for (int s = 0; s + 3 < NSTEP1; s += 2) {   // s = 0,2,...,44 -> steps 0..45
    STEP(s, bvA, bvB);
    STEP(s + 1, bvB, bvA);
  }
  STEP(NSTEP1 - 3, bvA, bvB);                 // s=46: loads B(48)->bvB, stages A(47)
  { // s = 47: stage A(48) into buf0; no more B loads; full drain at the end
    {
      bf16x8 af0[5], bf0[4];
      RDFRAGS(1, 0, af0, bf0);
      stageA(NSTEP1 - 1, 0);
      __builtin_amdgcn_s_barrier();
      asm volatile("s_waitcnt lgkmcnt(0)" ::: "memory");
      __builtin_amdgcn_sched_barrier(0);
      __builtin_amdgcn_s_setprio(1);
      MFMAH(af0, bf0);
      __builtin_amdgcn_s_setprio(0);
    }
    {
      bf16x8 af1[5], bf1[4];
      RDFRAGS(1, 1, af1, bf1);
      __builtin_amdgcn_s_barrier();
      asm volatile("s_waitcnt lgkmcnt(0)" ::: "memory");
      __builtin_amdgcn_sched_barrier(0);
      __builtin_amdgcn_s_setprio(1);
      MFMAH(af1, bf1);
      __builtin_amdgcn_s_setprio(0);
    }
    WRITEB(bvB, 0);
    asm volatile("s_waitcnt vmcnt(0) lgkmcnt(0)" ::: "memory");
    __builtin_amdgcn_s_barrier();
    __builtin_amdgcn_sched_barrier(0);
  }
  { // s = 48: plain compute of buf0
    bf16x8 af0[5], bf0[4], af1[5], bf1[4];
    RDFRAGS(0, 0, af0, bf0);
    MFMAH(af0, bf0);
    RDFRAGS(0, 1, af1, bf1);
    MFMAH(af1, bf1);
  }

#undef STEP
#undef LOADB
#undef WRITEB
#undef RDFRAGS
#undef MFMAH

  float* dst = part + (size_t)kc * NP * HID;
  #pragma unroll
  for (int fm = 0; fm < 5; ++fm) {
    #pragma unroll
    for (int fn = 0; fn < 4; ++fn) {
      int ncol = n0 + wn*64 + fn*16 + (lane & 15);
      #pragma unroll
      for (int j = 0; j < 4; ++j) {
        int m = wm*80 + fm*16 + ((lane >> 4) * 4) + j;
        if (m < NP && ncol < HID)
          dst[(size_t)m * HID + ncol] = acc[fm][fn][j];
      }
    }
  }
}

// ---------------- reduce 8 partials + bias + relu -> h bf16 [320][4096] ----------------
__global__ void reduce_k(const float* __restrict__ part,
                         const float* __restrict__ b1,
                         unsigned short* __restrict__ hb) {
  int n = blockIdx.x * 256 + threadIdx.x;
  int p = blockIdx.y;
  if (n >= K2PAD) return;
  float v = 0.0f;
  if (n < HID) {
    size_t i = (size_t)p * HID + n;
    const size_t S = (size_t)NP * HID;
    float s0 = 0.f;
    #pragma unroll
    for (int k = 0; k < KSPLIT1; ++k) s0 += part[i + (size_t)k*S];
    v = fmaxf(s0 + b1[n], 0.0f);
  }
  hb[(size_t)p * K2PAD + n] = f2bf(v);
}

// ---------------- GEMM2 (MFMA split-K): hb[320][4096] x [Wc|Wr|0][4096][128] -> part2 ----------------
__global__ __launch_bounds__(512, 1)
void gemm2_k(const unsigned short* __restrict__ hb,
             const float* __restrict__ Wc,
             const float* __restrict__ Wr,
             float* __restrict__ part2) {
  __shared__ char lds[2*BUFBYTES];
  const int t = threadIdx.x;
  const int wave = t >> 6;
  const int lane = t & 63;
  const int ntile = blockIdx.x;
  const int kc = blockIdx.y;
  const int n0 = ntile * BN;
  const int kstart0 = kc * KC2;

  const int bn_l = t & 63;
  const int bk8  = (t >> 6) * 8;
  const int jn   = n0 + bn_l;
  const float* bsrc; int bst;
  if (jn < 21)        { bsrc = Wc + jn;        bst = 21; }
  else if (jn < 101)  { bsrc = Wr + (jn - 21); bst = 80; }
  else                { bsrc = nullptr;        bst = 0;  }
  const int bwoff = ABYTES + bn_l*128 + ((bk8*2) ^ ((bn_l & 7) << 4));

  const int wm = wave >> 1;
  const int wn = wave & 1;

  int aoff[5][2], boff[2][2];
  #pragma unroll
  for (int fm = 0; fm < 5; ++fm) {
    int row = wm*80 + fm*16 + (lane & 15);
    #pragma unroll
    for (int h = 0; h < 2; ++h) {
      int kb = (h << 6) | ((lane >> 4) << 4);
      aoff[fm][h] = row*128 + (kb ^ ((row & 7) << 4));
    }
  }
  #pragma unroll
  for (int fn = 0; fn < 2; ++fn) {
    int col = wn*32 + fn*16 + (lane & 15);
    #pragma unroll
    for (int h = 0; h < 2; ++h) {
      int kb = (h << 6) | ((lane >> 4) << 4);
      boff[fn][h] = ABYTES + col*128 + (kb ^ ((col & 7) << 4));
    }
  }

  f32x4 acc[5][2];
  #pragma unroll
  for (int fm=0; fm<5; ++fm)
    #pragma unroll
    for (int fn=0; fn<2; ++fn)
      acc[fm][fn] = (f32x4){0.f,0.f,0.f,0.f};

  auto stageA = [&](int s, int buf) {
    const int kstart = kstart0 + s*BK;
    char* dstbase = lds + buf*BUFBYTES;
    #pragma unroll
    for (int i = 0; i < 5; ++i) {
      int chunk = wave*5 + i;
      int o = chunk*1024 + lane*16;
      int row = o >> 7;
      int kb = (o & 127) ^ ((row & 7) << 4);
      const char* g = (const char*)hb + (size_t)row*(K2PAD*2) + (size_t)kstart*2 + kb;
      __builtin_amdgcn_global_load_lds(
          (const __attribute__((address_space(1))) unsigned int*)g,
          (__attribute__((address_space(3))) unsigned int*)(dstbase + chunk*1024),
          16, 0, 0);
    }
  };
  auto loadB = [&](int s, float* bv) {
    const int kstart = kstart0 + s*BK;
    #pragma unroll
    for (int i = 0; i < 8; ++i) {
      int k = kstart + bk8 + i;
      bv[i] = (bsrc && k < HID) ? bsrc[(size_t)k * bst] : 0.0f;
    }
  };
  auto writeB = [&](const float* bv, int buf) {
    bf16x8 bb;
    #pragma unroll
    for (int i = 0; i < 8; ++i) bb[i] = (short)f2bf(bv[i]);
    *(bf16x8*)(lds + buf*BUFBYTES + bwoff) = bb;
  };
  auto compute = [&](int buf) {
    const char* base = lds + buf*BUFBYTES;
    #pragma unroll
    for (int h = 0; h < 2; ++h) {
      bf16x8 af[5], bfr[2];
      #pragma unroll
      for (int fm = 0; fm < 5; ++fm) af[fm] = *(const bf16x8*)(base + aoff[fm][h]);
      #pragma unroll
      for (int fn = 0; fn < 2; ++fn) bfr[fn] = *(const bf16x8*)(base + boff[fn][h]);
      #pragma unroll
      for (int fm = 0; fm < 5; ++fm)
        #pragma unroll
        for (int fn = 0; fn < 2; ++fn)
          acc[fm][fn] = __builtin_amdgcn_mfma_f32_16x16x32_bf16(af[fm], bfr[fn], acc[fm][fn], 0, 0, 0);
    }
  };

  {
    float bv[8];
    loadB(0, bv);
    stageA(0, 0);
    writeB(bv, 0);
  }
  __syncthreads();

  for (int s = 0; s < NSTEP2; ++s) {
    int cur = s & 1;
    float bv[8];
    if (s + 1 < NSTEP2) {
      loadB(s+1, bv);
      stageA(s+1, cur^1);
    }
    compute(cur);
    if (s + 1 < NSTEP2) {
      writeB(bv, cur^1);
    }
    __syncthreads();
  }

  float* dst = part2 + (size_t)kc * PM * 128;
  #pragma unroll
  for (int fm = 0; fm < 5; ++fm) {
    #pragma unroll
    for (int fn = 0; fn < 2; ++fn) {
      int ncol = n0 + wn*32 + fn*16 + (lane & 15);
      #pragma unroll
      for (int j = 0; j < 4; ++j) {
        int m = wm*80 + fm*16 + ((lane >> 4) * 4) + j;
        dst[(size_t)m * 128 + ncol] = acc[fm][fn][j];
      }
    }
  }
}

// ---------------- reduce2: sum K-slices + bias -> out ----------------
__global__ void reduce2_k(const float* __restrict__ part2,
                          const float* __restrict__ bc,
                          const float* __restrict__ br,
                          float* __restrict__ out) {
  int p = blockIdx.x;
  int j = threadIdx.x;
  if (j >= 101) return;
  float s = 0.0f;
  #pragma unroll 8
  for (int k = 0; k < KSL; ++k)
    s += part2[(size_t)k * PM * 128 + (size_t)p * 128 + j];
  if (j < 21) out[(size_t)p*21 + j] = s + bc[j];
  else        out[6300 + (size_t)p*80 + (j-21)] = s + br[j-21];
}

extern "C" void kernel_launch(void* const* d_in, const int* in_sizes, int n_in,
                              void* d_out, int out_size, void* d_ws, size_t ws_size,
                              hipStream_t stream) {
  const float* fmap  = (const float*)d_in[0];
  const float* props = (const float*)d_in[1];
  const float* W1    = (const float*)d_in[2];
  const float* b1    = (const float*)d_in[3];
  const float* Wc    = (const float*)d_in[4];
  const float* bc    = (const float*)d_in[5];
  const float* Wr    = (const float*)d_in[6];
  const float* br    = (const float*)d_in[7];
  float* out = (float*)d_out;
  char* ws = (char*)d_ws;

  unsigned short* pooled = (unsigned short*)ws;                     // 16,056,320 B
  float* part = (float*)(ws + 16056320);                            // 8*300*4069*4 = 39,062,400 B
  unsigned short* hb = (unsigned short*)(ws + 16056320 + 39062400); //  2,621,440 B
  float* part2 = (float*)(ws + 16056320 + 39062400 + 2621440);      //  5,242,880 B

  roi_pool_k<<<PM, 256, 0, stream>>>(fmap, props, pooled);
  gemm1_k<<<256, 512, 0, stream>>>(pooled, W1, part);
  reduce_k<<<dim3(K2PAD/256, NP), 256, 0, stream>>>(part, b1, hb);
  gemm2_k<<<dim3(2, KSL), 512, 0, stream>>>(hb, Wc, Wr, part2);
  reduce2_k<<<NP, 128, 0, stream>>>(part2, bc, br, out);
}